// Round 1
// baseline (2321.317 us; speedup 1.0000x reference)
//
#include <hip/hip_runtime.h>

#define HH 448
#define WW 608
#define CIN 64
#define D1 128
#define D2 128
#define D3 1024
#define HWPROD (HH*WW)          // 272384

typedef __bf16 bf16x8 __attribute__((ext_vector_type(8)));
typedef float  f32x4  __attribute__((ext_vector_type(4)));

__device__ inline unsigned short f2bf(float v) {
    __bf16 b = (__bf16)v;
    return __builtin_bit_cast(unsigned short, b);
}

__device__ inline float lrelu(float v) { return v > 0.f ? v : 0.01f * v; }

// 8 contiguous f32 -> bf16x8
__device__ inline bf16x8 cvt8c(const float* __restrict__ p) {
    f32x4 f0 = *reinterpret_cast<const f32x4*>(p);
    f32x4 f1 = *reinterpret_cast<const f32x4*>(p + 4);
    bf16x8 r;
    r[0] = (__bf16)f0[0]; r[1] = (__bf16)f0[1]; r[2] = (__bf16)f0[2]; r[3] = (__bf16)f0[3];
    r[4] = (__bf16)f1[0]; r[5] = (__bf16)f1[1]; r[6] = (__bf16)f1[2]; r[7] = (__bf16)f1[3];
    return r;
}

// 8 strided f32 -> bf16x8
__device__ inline bf16x8 cvt8s(const float* __restrict__ p, int stride) {
    bf16x8 r;
    #pragma unroll
    for (int j = 0; j < 8; ++j) r[j] = (__bf16)p[j * stride];
    return r;
}

__device__ inline bf16x8 zero8() {
    bf16x8 r;
    #pragma unroll
    for (int j = 0; j < 8; ++j) r[j] = (__bf16)0.f;
    return r;
}

// ---------------- Stage 1: conv3x3 64->128 + b1 + lrelu -> y1[h][w][d] bf16 ----
__global__ __launch_bounds__(256) void conv_kernel(
    const float* __restrict__ x, const float* __restrict__ w1,
    const float* __restrict__ b1, unsigned short* __restrict__ y1)
{
    const int h  = blockIdx.z;
    const int dt = blockIdx.y;      // 0..1  (d block of 64)
    const int wt = blockIdx.x;      // 0..9  (w block of 64)
    const int lane = threadIdx.x & 63;
    const int wv   = threadIdx.x >> 6;
    const int wm = wv >> 1, wn = wv & 1;
    const int l15 = lane & 15, lg = lane >> 4;

    const int d_base = dt * 64 + wm * 32;
    const int w_base = wt * 64 + wn * 32;

    f32x4 acc[2][2] = {};

    for (int ty = 0; ty < 3; ++ty) {
        const int hs = h + ty - 1;
        const bool hok = (unsigned)hs < (unsigned)HH;
        for (int tx = 0; tx < 3; ++tx) {
            #pragma unroll
            for (int kc = 0; kc < 2; ++kc) {
                const int c0 = kc * 32 + lg * 8;
                bf16x8 afrag[2];
                #pragma unroll
                for (int sm = 0; sm < 2; ++sm) {
                    const int d = d_base + sm * 16 + l15;
                    afrag[sm] = cvt8s(w1 + d * 576 + c0 * 9 + ty * 3 + tx, 9);
                }
                bf16x8 bfrag[2];
                #pragma unroll
                for (int sn = 0; sn < 2; ++sn) {
                    const int wsrc = w_base + sn * 16 + l15 + tx - 1;
                    if (hok && (unsigned)wsrc < (unsigned)WW) {
                        bfrag[sn] = cvt8s(x + c0 * HWPROD + hs * WW + wsrc, HWPROD);
                    } else {
                        bfrag[sn] = zero8();
                    }
                }
                #pragma unroll
                for (int sm = 0; sm < 2; ++sm)
                    #pragma unroll
                    for (int sn = 0; sn < 2; ++sn)
                        acc[sm][sn] = __builtin_amdgcn_mfma_f32_16x16x32_bf16(
                            afrag[sm], bfrag[sn], acc[sm][sn], 0, 0, 0);
            }
        }
    }

    #pragma unroll
    for (int sm = 0; sm < 2; ++sm) {
        const int dq = d_base + sm * 16 + lg * 4;
        #pragma unroll
        for (int sn = 0; sn < 2; ++sn) {
            const int w = w_base + sn * 16 + l15;
            if (w < WW) {
                #pragma unroll
                for (int r = 0; r < 4; ++r) {
                    const int d = dq + r;
                    float v = acc[sm][sn][r] + b1[d];
                    y1[(h * WW + w) * D1 + d] = f2bf(lrelu(v));
                }
            }
        }
    }
}

// ---------------- Stage 2: y2[h][w][d] = lrelu(W2[h] @ y1[h] + b2[h]) ---------
__global__ __launch_bounds__(256) void gemm2_kernel(
    const unsigned short* __restrict__ y1, const float* __restrict__ w2,
    const float* __restrict__ b2, unsigned short* __restrict__ y2)
{
    const int h  = blockIdx.z;
    const int mt = blockIdx.y;      // 0..1
    const int wt = blockIdx.x;      // 0..9
    const int lane = threadIdx.x & 63;
    const int wv   = threadIdx.x >> 6;
    const int wm = wv >> 1, wn = wv & 1;
    const int l15 = lane & 15, lg = lane >> 4;

    const int d_base = mt * 64 + wm * 32;
    const int w_base = wt * 64 + wn * 32;
    const float* __restrict__ Wh = w2 + h * (D2 * D1);

    f32x4 acc[2][2] = {};

    #pragma unroll
    for (int kc = 0; kc < 4; ++kc) {
        const int c0 = kc * 32 + lg * 8;
        bf16x8 afrag[2];
        #pragma unroll
        for (int sm = 0; sm < 2; ++sm) {
            const int d = d_base + sm * 16 + l15;
            afrag[sm] = cvt8c(Wh + d * D1 + c0);
        }
        bf16x8 bfrag[2];
        #pragma unroll
        for (int sn = 0; sn < 2; ++sn) {
            const int w = w_base + sn * 16 + l15;
            if (w < WW)
                bfrag[sn] = *reinterpret_cast<const bf16x8*>(y1 + (h * WW + w) * D1 + c0);
            else
                bfrag[sn] = zero8();
        }
        #pragma unroll
        for (int sm = 0; sm < 2; ++sm)
            #pragma unroll
            for (int sn = 0; sn < 2; ++sn)
                acc[sm][sn] = __builtin_amdgcn_mfma_f32_16x16x32_bf16(
                    afrag[sm], bfrag[sn], acc[sm][sn], 0, 0, 0);
    }

    #pragma unroll
    for (int sm = 0; sm < 2; ++sm) {
        const int dq = d_base + sm * 16 + lg * 4;
        #pragma unroll
        for (int sn = 0; sn < 2; ++sn) {
            const int w = w_base + sn * 16 + l15;
            if (w < WW) {
                #pragma unroll
                for (int r = 0; r < 4; ++r) {
                    const int d = dq + r;
                    float v = acc[sm][sn][r] + b2[h * D2 + d];
                    y2[(h * WW + w) * D2 + d] = f2bf(lrelu(v));
                }
            }
        }
    }
}

// ------- Stage 3+4 fused: y3 tile in regs -> layer-4 partial sums per e-tile --
__global__ __launch_bounds__(256) void gemm3_kernel(
    const unsigned short* __restrict__ y2, const float* __restrict__ w3,
    const float* __restrict__ b3, const float* __restrict__ w4,
    float* __restrict__ part)
{
    const int h  = blockIdx.z;
    const int mt = blockIdx.y;      // 0..15 (e block of 64)
    const int wt = blockIdx.x;      // 0..9
    const int lane = threadIdx.x & 63;
    const int wv   = threadIdx.x >> 6;
    const int wm = wv >> 1, wn = wv & 1;
    const int l15 = lane & 15, lg = lane >> 4;

    const int e_base = mt * 64 + wm * 32;
    const int w_base = wt * 64 + wn * 32;
    const float* __restrict__ Wh = w3 + h * (D3 * D2);

    __shared__ float sm_buf[2][64];
    if (threadIdx.x < 128) sm_buf[threadIdx.x >> 6][threadIdx.x & 63] = 0.f;
    __syncthreads();

    f32x4 acc[2][2] = {};

    #pragma unroll
    for (int kc = 0; kc < 4; ++kc) {
        const int c0 = kc * 32 + lg * 8;
        bf16x8 afrag[2];
        #pragma unroll
        for (int sm = 0; sm < 2; ++sm) {
            const int e = e_base + sm * 16 + l15;
            afrag[sm] = cvt8c(Wh + e * D2 + c0);
        }
        bf16x8 bfrag[2];
        #pragma unroll
        for (int sn = 0; sn < 2; ++sn) {
            const int w = w_base + sn * 16 + l15;
            if (w < WW)
                bfrag[sn] = *reinterpret_cast<const bf16x8*>(y2 + (h * WW + w) * D2 + c0);
            else
                bfrag[sn] = zero8();
        }
        #pragma unroll
        for (int sm = 0; sm < 2; ++sm)
            #pragma unroll
            for (int sn = 0; sn < 2; ++sn)
                acc[sm][sn] = __builtin_amdgcn_mfma_f32_16x16x32_bf16(
                    afrag[sm], bfrag[sn], acc[sm][sn], 0, 0, 0);
    }

    // epilogue: v = lrelu(acc + b3[h][e]); accumulate w4[h][k][e]*v into per-w sums
    const float* __restrict__ b3h = b3 + h * D3;
    const float* __restrict__ w4h = w4 + h * 2 * D3;

    #pragma unroll
    for (int sn = 0; sn < 2; ++sn) {
        const int wcol = wn * 32 + sn * 16 + l15;   // 0..63 within block
        float p0 = 0.f, p1 = 0.f;
        #pragma unroll
        for (int sm = 0; sm < 2; ++sm) {
            const int eq = e_base + sm * 16 + lg * 4;
            #pragma unroll
            for (int r = 0; r < 4; ++r) {
                const int e = eq + r;
                float v = lrelu(acc[sm][sn][r] + b3h[e]);
                p0 += w4h[e] * v;
                p1 += w4h[D3 + e] * v;
            }
        }
        atomicAdd(&sm_buf[0][wcol], p0);
        atomicAdd(&sm_buf[1][wcol], p1);
    }
    __syncthreads();

    if (threadIdx.x < 128) {
        const int k  = threadIdx.x >> 6;
        const int wl = threadIdx.x & 63;
        const int w  = wt * 64 + wl;
        if (w < WW)
            part[((h * 16 + mt) * 2 + k) * WW + w] = sm_buf[k][wl];
    }
}

// ---------------- Stage 5: reduce 16 partials + b4; out & lrelu(mask) ---------
__global__ __launch_bounds__(256) void final_kernel(
    const float* __restrict__ part, const float* __restrict__ b4,
    float* __restrict__ out)
{
    const int idx = blockIdx.x * 256 + threadIdx.x;
    if (idx >= HH * WW) return;
    const int h = idx / WW;
    const int w = idx - h * WW;
    float s0 = 0.f, s1 = 0.f;
    #pragma unroll
    for (int t = 0; t < 16; ++t) {
        s0 += part[((h * 16 + t) * 2 + 0) * WW + w];
        s1 += part[((h * 16 + t) * 2 + 1) * WW + w];
    }
    s0 += b4[h * 2 + 0];
    s1 += b4[h * 2 + 1];
    out[idx] = s0;
    out[HH * WW + idx] = lrelu(s1);
}

extern "C" void kernel_launch(void* const* d_in, const int* in_sizes, int n_in,
                              void* d_out, int out_size, void* d_ws, size_t ws_size,
                              hipStream_t stream) {
    const float* x  = (const float*)d_in[0];
    const float* w1 = (const float*)d_in[1];
    const float* b1 = (const float*)d_in[2];
    const float* w2 = (const float*)d_in[3];
    const float* b2 = (const float*)d_in[4];
    const float* w3 = (const float*)d_in[5];
    const float* b3 = (const float*)d_in[6];
    const float* w4 = (const float*)d_in[7];
    const float* b4 = (const float*)d_in[8];
    float* out = (float*)d_out;

    unsigned short* y1 = (unsigned short*)d_ws;                  // 448*608*128 bf16
    unsigned short* y2 = y1 + (size_t)HH * WW * D1;              // 448*608*128 bf16
    float* part = (float*)(y2 + (size_t)HH * WW * D2);           // 448*16*2*608 f32

    conv_kernel <<<dim3(10, 2, HH), 256, 0, stream>>>(x, w1, b1, y1);
    gemm2_kernel<<<dim3(10, 2, HH), 256, 0, stream>>>(y1, w2, b2, y2);
    gemm3_kernel<<<dim3(10, 16, HH), 256, 0, stream>>>(y2, w3, b3, w4, part);
    final_kernel<<<(HH * WW + 255) / 256, 256, 0, stream>>>(part, b4, out);
}

// Round 2
// 1121.166 us; speedup vs baseline: 2.0704x; 2.0704x over previous
//
#include <hip/hip_runtime.h>

#define HH 448
#define WW 608
#define CIN 64
#define D1 128
#define D2 128
#define D3 1024
#define HWPROD (HH*WW)          // 272384

typedef __bf16 bf16x8 __attribute__((ext_vector_type(8)));
typedef float  f32x4  __attribute__((ext_vector_type(4)));

__device__ inline unsigned short f2bf(float v) {
    __bf16 b = (__bf16)v;
    return __builtin_bit_cast(unsigned short, b);
}

__device__ inline float lrelu(float v) { return v > 0.f ? v : 0.01f * v; }

// 8 contiguous f32 -> bf16x8
__device__ inline bf16x8 cvt8c(const float* __restrict__ p) {
    f32x4 f0 = *reinterpret_cast<const f32x4*>(p);
    f32x4 f1 = *reinterpret_cast<const f32x4*>(p + 4);
    bf16x8 r;
    r[0] = (__bf16)f0[0]; r[1] = (__bf16)f0[1]; r[2] = (__bf16)f0[2]; r[3] = (__bf16)f0[3];
    r[4] = (__bf16)f1[0]; r[5] = (__bf16)f1[1]; r[6] = (__bf16)f1[2]; r[7] = (__bf16)f1[3];
    return r;
}

__device__ inline bf16x8 zero8() {
    bf16x8 r;
    #pragma unroll
    for (int j = 0; j < 8; ++j) r[j] = (__bf16)0.f;
    return r;
}

// ------------- prep: x[c][h][w] f32 -> xt[h*w][c] bf16 ------------------------
__global__ __launch_bounds__(256) void transpose_x_kernel(
    const float* __restrict__ x, unsigned short* __restrict__ xt)
{
    const int pos = blockIdx.x * 256 + threadIdx.x;       // HWPROD divisible by 256
    #pragma unroll
    for (int c8 = 0; c8 < 8; ++c8) {
        bf16x8 r;
        #pragma unroll
        for (int j = 0; j < 8; ++j)
            r[j] = (__bf16)x[(size_t)(c8 * 8 + j) * HWPROD + pos];
        *reinterpret_cast<bf16x8*>(xt + (size_t)pos * 64 + c8 * 8) = r;
    }
}

// ------------- prep: w1[d][c][3][3] f32 -> w1t[tap][d][c] bf16 ----------------
__global__ __launch_bounds__(256) void convert_w1_kernel(
    const float* __restrict__ w1, unsigned short* __restrict__ w1t)
{
    const int idx = blockIdx.x * 256 + threadIdx.x;       // 9*128*64 = 73728
    if (idx >= 9 * D1 * 64) return;
    const int tap = idx / (D1 * 64);
    const int rem = idx - tap * (D1 * 64);
    const int d = rem >> 6, c = rem & 63;
    w1t[idx] = f2bf(w1[(d * 64 + c) * 9 + tap]);
}

// ------------- prep: generic contiguous f32 -> bf16 (n8 groups of 8) ----------
__global__ __launch_bounds__(256) void cvt_bf16_kernel(
    const float* __restrict__ in, unsigned short* __restrict__ out, int n8)
{
    const int i = blockIdx.x * 256 + threadIdx.x;
    if (i >= n8) return;
    *reinterpret_cast<bf16x8*>(out + (size_t)i * 8) = cvt8c(in + (size_t)i * 8);
}

// ---------------- Stage 1: conv3x3 64->128 + b1 + lrelu -> y1[h][w][d] bf16 ----
__global__ __launch_bounds__(256) void conv_kernel(
    const unsigned short* __restrict__ xt, const unsigned short* __restrict__ w1t,
    const float* __restrict__ b1, unsigned short* __restrict__ y1)
{
    const int h  = blockIdx.z;
    const int dt = blockIdx.y;      // 0..1  (d block of 64)
    const int wt = blockIdx.x;      // 0..9  (w block of 64)
    const int lane = threadIdx.x & 63;
    const int wv   = threadIdx.x >> 6;
    const int wm = wv >> 1, wn = wv & 1;
    const int l15 = lane & 15, lg = lane >> 4;

    const int d_base = dt * 64 + wm * 32;
    const int w_base = wt * 64 + wn * 32;

    f32x4 acc[2][2] = {};

    #pragma unroll
    for (int tap = 0; tap < 9; ++tap) {
        const int ty = tap / 3, tx = tap - ty * 3;
        const int hs = h + ty - 1;
        const bool hok = (unsigned)hs < (unsigned)HH;
        #pragma unroll
        for (int kc = 0; kc < 2; ++kc) {
            const int c0 = kc * 32 + lg * 8;
            bf16x8 afrag[2];
            #pragma unroll
            for (int sm = 0; sm < 2; ++sm) {
                const int d = d_base + sm * 16 + l15;
                afrag[sm] = *reinterpret_cast<const bf16x8*>(
                    w1t + ((size_t)tap * D1 + d) * 64 + c0);
            }
            bf16x8 bfrag[2];
            #pragma unroll
            for (int sn = 0; sn < 2; ++sn) {
                const int wsrc = w_base + sn * 16 + l15 + tx - 1;
                if (hok && (unsigned)wsrc < (unsigned)WW)
                    bfrag[sn] = *reinterpret_cast<const bf16x8*>(
                        xt + ((size_t)hs * WW + wsrc) * 64 + c0);
                else
                    bfrag[sn] = zero8();
            }
            #pragma unroll
            for (int sm = 0; sm < 2; ++sm)
                #pragma unroll
                for (int sn = 0; sn < 2; ++sn)
                    acc[sm][sn] = __builtin_amdgcn_mfma_f32_16x16x32_bf16(
                        afrag[sm], bfrag[sn], acc[sm][sn], 0, 0, 0);
        }
    }

    #pragma unroll
    for (int sm = 0; sm < 2; ++sm) {
        const int dq = d_base + sm * 16 + lg * 4;
        #pragma unroll
        for (int sn = 0; sn < 2; ++sn) {
            const int w = w_base + sn * 16 + l15;
            if (w < WW) {
                #pragma unroll
                for (int r = 0; r < 4; ++r) {
                    const int d = dq + r;
                    float v = acc[sm][sn][r] + b1[d];
                    y1[((size_t)h * WW + w) * D1 + d] = f2bf(lrelu(v));
                }
            }
        }
    }
}

// ---------------- Stage 2: y2[h][w][d] = lrelu(W2[h] @ y1[h] + b2[h]) ---------
__global__ __launch_bounds__(256) void gemm2_kernel(
    const unsigned short* __restrict__ y1, const unsigned short* __restrict__ w2b,
    const float* __restrict__ b2, unsigned short* __restrict__ y2)
{
    const int h  = blockIdx.z;
    const int mt = blockIdx.y;      // 0..1
    const int wt = blockIdx.x;      // 0..9
    const int lane = threadIdx.x & 63;
    const int wv   = threadIdx.x >> 6;
    const int wm = wv >> 1, wn = wv & 1;
    const int l15 = lane & 15, lg = lane >> 4;

    const int d_base = mt * 64 + wm * 32;
    const int w_base = wt * 64 + wn * 32;
    const unsigned short* __restrict__ Wh = w2b + (size_t)h * (D2 * D1);

    f32x4 acc[2][2] = {};

    #pragma unroll
    for (int kc = 0; kc < 4; ++kc) {
        const int c0 = kc * 32 + lg * 8;
        bf16x8 afrag[2];
        #pragma unroll
        for (int sm = 0; sm < 2; ++sm) {
            const int d = d_base + sm * 16 + l15;
            afrag[sm] = *reinterpret_cast<const bf16x8*>(Wh + (size_t)d * D1 + c0);
        }
        bf16x8 bfrag[2];
        #pragma unroll
        for (int sn = 0; sn < 2; ++sn) {
            const int w = w_base + sn * 16 + l15;
            if (w < WW)
                bfrag[sn] = *reinterpret_cast<const bf16x8*>(y1 + ((size_t)h * WW + w) * D1 + c0);
            else
                bfrag[sn] = zero8();
        }
        #pragma unroll
        for (int sm = 0; sm < 2; ++sm)
            #pragma unroll
            for (int sn = 0; sn < 2; ++sn)
                acc[sm][sn] = __builtin_amdgcn_mfma_f32_16x16x32_bf16(
                    afrag[sm], bfrag[sn], acc[sm][sn], 0, 0, 0);
    }

    #pragma unroll
    for (int sm = 0; sm < 2; ++sm) {
        const int dq = d_base + sm * 16 + lg * 4;
        #pragma unroll
        for (int sn = 0; sn < 2; ++sn) {
            const int w = w_base + sn * 16 + l15;
            if (w < WW) {
                #pragma unroll
                for (int r = 0; r < 4; ++r) {
                    const int d = dq + r;
                    float v = acc[sm][sn][r] + b2[(size_t)h * D2 + d];
                    y2[((size_t)h * WW + w) * D2 + d] = f2bf(lrelu(v));
                }
            }
        }
    }
}

// ------- Stage 3+4 fused: y3 tile in regs -> layer-4 partial sums per e-tile --
template<bool W3BF16>
__global__ __launch_bounds__(256) void gemm3_kernel(
    const unsigned short* __restrict__ y2, const void* __restrict__ w3v,
    const float* __restrict__ b3, const float* __restrict__ w4,
    float* __restrict__ part)
{
    const int h  = blockIdx.z;
    const int mt = blockIdx.y;      // 0..15 (e block of 64)
    const int wt = blockIdx.x;      // 0..9
    const int lane = threadIdx.x & 63;
    const int wv   = threadIdx.x >> 6;
    const int wm = wv >> 1, wn = wv & 1;
    const int l15 = lane & 15, lg = lane >> 4;

    const int e_base = mt * 64 + wm * 32;
    const int w_base = wt * 64 + wn * 32;

    __shared__ float sm_buf[2][64];
    if (threadIdx.x < 128) sm_buf[threadIdx.x >> 6][threadIdx.x & 63] = 0.f;
    __syncthreads();

    f32x4 acc[2][2] = {};

    #pragma unroll
    for (int kc = 0; kc < 4; ++kc) {
        const int c0 = kc * 32 + lg * 8;
        bf16x8 afrag[2];
        #pragma unroll
        for (int sm = 0; sm < 2; ++sm) {
            const int e = e_base + sm * 16 + l15;
            if (W3BF16) {
                const unsigned short* w3b = (const unsigned short*)w3v;
                afrag[sm] = *reinterpret_cast<const bf16x8*>(
                    w3b + ((size_t)h * D3 + e) * D2 + c0);
            } else {
                const float* w3 = (const float*)w3v;
                afrag[sm] = cvt8c(w3 + ((size_t)h * D3 + e) * D2 + c0);
            }
        }
        bf16x8 bfrag[2];
        #pragma unroll
        for (int sn = 0; sn < 2; ++sn) {
            const int w = w_base + sn * 16 + l15;
            if (w < WW)
                bfrag[sn] = *reinterpret_cast<const bf16x8*>(y2 + ((size_t)h * WW + w) * D2 + c0);
            else
                bfrag[sn] = zero8();
        }
        #pragma unroll
        for (int sm = 0; sm < 2; ++sm)
            #pragma unroll
            for (int sn = 0; sn < 2; ++sn)
                acc[sm][sn] = __builtin_amdgcn_mfma_f32_16x16x32_bf16(
                    afrag[sm], bfrag[sn], acc[sm][sn], 0, 0, 0);
    }

    // epilogue: v = lrelu(acc + b3[h][e]); accumulate w4[h][k][e]*v into per-w sums
    const float* __restrict__ b3h = b3 + (size_t)h * D3;
    const float* __restrict__ w4h = w4 + (size_t)h * 2 * D3;

    #pragma unroll
    for (int sn = 0; sn < 2; ++sn) {
        const int wcol = wn * 32 + sn * 16 + l15;   // 0..63 within block
        float p0 = 0.f, p1 = 0.f;
        #pragma unroll
        for (int sm = 0; sm < 2; ++sm) {
            const int eq = e_base + sm * 16 + lg * 4;
            #pragma unroll
            for (int r = 0; r < 4; ++r) {
                const int e = eq + r;
                float v = lrelu(acc[sm][sn][r] + b3h[e]);
                p0 += w4h[e] * v;
                p1 += w4h[D3 + e] * v;
            }
        }
        atomicAdd(&sm_buf[0][wcol], p0);
        atomicAdd(&sm_buf[1][wcol], p1);
    }
    __syncthreads();

    if (threadIdx.x < 128) {
        const int k  = threadIdx.x >> 6;
        const int wl = threadIdx.x & 63;
        const int w  = wt * 64 + wl;
        if (w < WW)
            part[(((size_t)h * 16 + mt) * 2 + k) * WW + w] = sm_buf[k][wl];
    }
}

// ---------------- Stage 5: reduce 16 partials + b4; out & lrelu(mask) ---------
__global__ __launch_bounds__(256) void final_kernel(
    const float* __restrict__ part, const float* __restrict__ b4,
    float* __restrict__ out)
{
    const int idx = blockIdx.x * 256 + threadIdx.x;
    if (idx >= HH * WW) return;
    const int h = idx / WW;
    const int w = idx - h * WW;
    float s0 = 0.f, s1 = 0.f;
    #pragma unroll
    for (int t = 0; t < 16; ++t) {
        s0 += part[(((size_t)h * 16 + t) * 2 + 0) * WW + w];
        s1 += part[(((size_t)h * 16 + t) * 2 + 1) * WW + w];
    }
    s0 += b4[h * 2 + 0];
    s1 += b4[h * 2 + 1];
    out[idx] = s0;
    out[HH * WW + idx] = lrelu(s1);
}

extern "C" void kernel_launch(void* const* d_in, const int* in_sizes, int n_in,
                              void* d_out, int out_size, void* d_ws, size_t ws_size,
                              hipStream_t stream) {
    const float* x  = (const float*)d_in[0];
    const float* w1 = (const float*)d_in[1];
    const float* b1 = (const float*)d_in[2];
    const float* w2 = (const float*)d_in[3];
    const float* b2 = (const float*)d_in[4];
    const float* w3 = (const float*)d_in[5];
    const float* b3 = (const float*)d_in[6];
    const float* w4 = (const float*)d_in[7];
    const float* b4 = (const float*)d_in[8];
    float* out = (float*)d_out;

    char* ws = (char*)d_ws;
    size_t off = 0;
    unsigned short* y1 = (unsigned short*)(ws + off); off += (size_t)HWPROD * D1 * 2;   // 69.73 MB
    unsigned short* y2 = (unsigned short*)(ws + off); off += (size_t)HWPROD * D2 * 2;   // 69.73 MB
    // region A (34.87 MB): xt (bf16 HW*64) -> w2b (bf16 448*128*128) -> part (f32 448*16*2*608)
    char* regionA = ws + off; off += (size_t)HWPROD * 128;
    unsigned short* xt   = (unsigned short*)regionA;
    unsigned short* w2b  = (unsigned short*)regionA;
    float*          part = (float*)regionA;
    unsigned short* w1t = (unsigned short*)(ws + off); off += (size_t)9 * D1 * 64 * 2;  // 147 KB
    size_t base_need = off;
    size_t w3b_bytes = (size_t)HH * D3 * D2 * 2;                                        // 117.4 MB
    bool use_w3b = (ws_size >= base_need + w3b_bytes);
    unsigned short* w3b = (unsigned short*)(ws + base_need);

    // prep
    transpose_x_kernel<<<HWPROD / 256, 256, 0, stream>>>(x, xt);
    convert_w1_kernel<<<(9 * D1 * 64 + 255) / 256, 256, 0, stream>>>(w1, w1t);
    if (use_w3b) {
        int n8 = HH * D3 * D2 / 8;
        cvt_bf16_kernel<<<(n8 + 255) / 256, 256, 0, stream>>>(w3, w3b, n8);
    }

    // stage 1
    conv_kernel<<<dim3(10, 2, HH), 256, 0, stream>>>(xt, w1t, b1, y1);

    // w2 -> bf16 into region A (xt now dead)
    {
        int n8 = HH * D2 * D1 / 8;
        cvt_bf16_kernel<<<(n8 + 255) / 256, 256, 0, stream>>>(w2, w2b, n8);
    }

    // stage 2
    gemm2_kernel<<<dim3(10, 2, HH), 256, 0, stream>>>(y1, w2b, b2, y2);

    // stage 3+4 (part overwrites region A; w2b dead)
    if (use_w3b)
        gemm3_kernel<true><<<dim3(10, 16, HH), 256, 0, stream>>>(y2, w3b, b3, w4, part);
    else
        gemm3_kernel<false><<<dim3(10, 16, HH), 256, 0, stream>>>(y2, w3, b3, w4, part);

    // stage 5
    final_kernel<<<(HH * WW + 255) / 256, 256, 0, stream>>>(part, b4, out);
}

// Round 3
// 309.166 us; speedup vs baseline: 7.5083x; 3.6264x over previous
//
#include <hip/hip_runtime.h>

#define HH 448
#define WW 608
#define D1 128
#define D2 128
#define D3 1024
#define HWPROD (HH*WW)          // 272384
#define CONV_LW 306             // 304 + 2 halo

typedef __bf16 bf16x8 __attribute__((ext_vector_type(8)));
typedef float  f32x4  __attribute__((ext_vector_type(4)));

__device__ inline unsigned short f2bf(float v) {
    __bf16 b = (__bf16)v;
    return __builtin_bit_cast(unsigned short, b);
}

// 8 contiguous f32 -> bf16x8
__device__ inline bf16x8 cvt8c(const float* __restrict__ p) {
    f32x4 f0 = *reinterpret_cast<const f32x4*>(p);
    f32x4 f1 = *reinterpret_cast<const f32x4*>(p + 4);
    bf16x8 r;
    r[0]=(__bf16)f0[0]; r[1]=(__bf16)f0[1]; r[2]=(__bf16)f0[2]; r[3]=(__bf16)f0[3];
    r[4]=(__bf16)f1[0]; r[5]=(__bf16)f1[1]; r[6]=(__bf16)f1[2]; r[7]=(__bf16)f1[3];
    return r;
}

// ------------- prep: x[c][h][w] f32 -> xt[h*w][c] bf16 ------------------------
__global__ __launch_bounds__(256) void transpose_x_kernel(
    const float* __restrict__ x, unsigned short* __restrict__ xt)
{
    const int pos = blockIdx.x * 256 + threadIdx.x;
    #pragma unroll
    for (int c8 = 0; c8 < 8; ++c8) {
        bf16x8 r;
        #pragma unroll
        for (int j = 0; j < 8; ++j)
            r[j] = (__bf16)x[(size_t)(c8 * 8 + j) * HWPROD + pos];
        *reinterpret_cast<bf16x8*>(xt + (size_t)pos * 64 + c8 * 8) = r;
    }
}

// ------------- prep: w1[d][c][3][3] f32 -> w1t[tap][d][c] bf16 ----------------
__global__ __launch_bounds__(256) void convert_w1_kernel(
    const float* __restrict__ w1, unsigned short* __restrict__ w1t)
{
    const int idx = blockIdx.x * 256 + threadIdx.x;
    if (idx >= 9 * D1 * 64) return;
    const int tap = idx / (D1 * 64);
    const int rem = idx - tap * (D1 * 64);
    const int d = rem >> 6, c = rem & 63;
    w1t[idx] = f2bf(w1[(d * 64 + c) * 9 + tap]);
}

// ---------------- Stage 1: conv3x3 64->128 + b1 + lrelu -> y1[h][w][d] bf16 ----
// one block per (w-half, h); LDS-staged 3 input rows with halo, XOR-swizzled
__global__ __launch_bounds__(512) void conv_kernel(
    const unsigned short* __restrict__ xt, const unsigned short* __restrict__ w1t,
    const float* __restrict__ b1, unsigned short* __restrict__ y1)
{
    __shared__ __align__(16) unsigned char lds[3 * CONV_LW * 128];   // 117504 B
    const int h      = blockIdx.y;
    const int wstart = blockIdx.x * 304;
    const int tid  = threadIdx.x;
    const int lane = tid & 63, wv = tid >> 6;
    const int l15 = lane & 15, lg = lane >> 4;
    const int wd = wv >> 2, wn = wv & 3;            // d-chunk 0..1, frag-set 0..3
    const int d0 = wd * 64;
    const int start = wn * 5;                        // frag sets {5,5,5,4}
    const int cnt   = (wn == 3) ? 4 : 5;

    // stage 3 rows x 306 cols x 64c (16B slots, swizzled slot ^= row&7)
    for (int s = tid; s < 3 * CONV_LW * 8; s += 512) {
        const int slot = s & 7;
        const int rw   = s >> 3;                     // LDS row 0..917
        const int ri   = rw / CONV_LW;
        const int wl   = rw - ri * CONV_LW;          // 0..305
        const int hs   = h + ri - 1;
        const int gw   = wstart + wl - 1;
        uint4 val = {0u, 0u, 0u, 0u};
        if ((unsigned)hs < (unsigned)HH && (unsigned)gw < (unsigned)WW)
            val = *reinterpret_cast<const uint4*>(xt + ((size_t)hs * WW + gw) * 64 + slot * 8);
        const int dslot = slot ^ (rw & 7);
        *reinterpret_cast<uint4*>(&lds[(size_t)rw * 128 + dslot * 16]) = val;
    }
    __syncthreads();

    f32x4 acc[5][4] = {};

    #pragma unroll
    for (int tap = 0; tap < 9; ++tap) {
        const int ty = tap / 3, tx = tap - ty * 3;
        bf16x8 a[4][2];
        #pragma unroll
        for (int mf = 0; mf < 4; ++mf)
            #pragma unroll
            for (int kc = 0; kc < 2; ++kc)
                a[mf][kc] = *reinterpret_cast<const bf16x8*>(
                    w1t + ((size_t)(tap * D1 + d0 + mf * 16 + l15)) * 64 + kc * 32 + lg * 8);
        #pragma unroll
        for (int f = 0; f < 5; ++f) {
            if (f < cnt) {
                const int col = (start + f) * 16 + l15;      // local out col 0..303
                const int row = ty * CONV_LW + col + tx;     // staged row
                bf16x8 b[2];
                #pragma unroll
                for (int kc = 0; kc < 2; ++kc) {
                    const int sl = (kc * 4 + lg) ^ (row & 7);
                    b[kc] = *reinterpret_cast<const bf16x8*>(&lds[(size_t)row * 128 + sl * 16]);
                }
                #pragma unroll
                for (int mf = 0; mf < 4; ++mf)
                    #pragma unroll
                    for (int kc = 0; kc < 2; ++kc)
                        acc[f][mf] = __builtin_amdgcn_mfma_f32_16x16x32_bf16(
                            a[mf][kc], b[kc], acc[f][mf], 0, 0, 0);
            }
        }
    }

    f32x4 b1v[4];
    #pragma unroll
    for (int mf = 0; mf < 4; ++mf)
        b1v[mf] = *reinterpret_cast<const f32x4*>(b1 + d0 + mf * 16 + lg * 4);

    #pragma unroll
    for (int f = 0; f < 5; ++f) {
        if (f < cnt) {
            const int w = wstart + (start + f) * 16 + l15;
            #pragma unroll
            for (int mf = 0; mf < 4; ++mf) {
                #pragma unroll
                for (int r = 0; r < 4; ++r) {
                    float v = acc[f][mf][r] + b1v[mf][r];
                    v = fmaxf(v, 0.01f * v);
                    y1[((size_t)h * WW + w) * D1 + d0 + mf * 16 + lg * 4 + r] = f2bf(v);
                }
            }
        }
    }
}

// ---------------- Stage 2: y2[h][w][d] = lrelu(W2[h] @ y1[h] + b2[h]) ---------
// one block per h; y1[h] staged in LDS; w2 read f32 + in-reg cvt
__global__ __launch_bounds__(512) void gemm2_kernel(
    const unsigned short* __restrict__ y1, const float* __restrict__ w2,
    const float* __restrict__ b2, unsigned short* __restrict__ y2)
{
    __shared__ __align__(16) unsigned char lds[WW * 256];            // 155648 B
    const int h = blockIdx.x;
    const int tid = threadIdx.x;
    const int lane = tid & 63, wv = tid >> 6;
    const int l15 = lane & 15, lg = lane >> 4;
    const int e0 = wv * 16;                          // 8 waves x 16 rows = 128

    // stage y1[h] (row = w, 256B; 16 slots of 16B; slot ^= row&7)
    {
        const unsigned char* src = reinterpret_cast<const unsigned char*>(y1 + (size_t)h * WW * D1);
        #pragma unroll
        for (int i = 0; i < 19; ++i) {
            const int byte = (i * 512 + tid) * 16;
            const int row  = byte >> 8;
            const int slot = (byte >> 4) & 15;
            uint4 val = *reinterpret_cast<const uint4*>(src + byte);
            const int dst = row * 256 + ((slot ^ (row & 7)) << 4);
            *reinterpret_cast<uint4*>(&lds[dst]) = val;
        }
    }

    // A fragments (this wave's 16 e-rows), f32 -> bf16
    bf16x8 a[4];
    #pragma unroll
    for (int kc = 0; kc < 4; ++kc)
        a[kc] = cvt8c(w2 + ((size_t)h * D2 + e0 + l15) * D1 + kc * 32 + lg * 8);
    f32x4 b2v = *reinterpret_cast<const f32x4*>(b2 + (size_t)h * D2 + e0 + lg * 4);

    __syncthreads();

    for (int nf = 0; nf < 38; ++nf) {
        const int w = nf * 16 + l15;
        bf16x8 b[4];
        #pragma unroll
        for (int kc = 0; kc < 4; ++kc) {
            const int sl = (kc * 4 + lg) ^ (w & 7);
            b[kc] = *reinterpret_cast<const bf16x8*>(&lds[(size_t)w * 256 + sl * 16]);
        }
        f32x4 t = {};
        #pragma unroll
        for (int kc = 0; kc < 4; ++kc)
            t = __builtin_amdgcn_mfma_f32_16x16x32_bf16(a[kc], b[kc], t, 0, 0, 0);
        #pragma unroll
        for (int r = 0; r < 4; ++r) {
            float v = t[r] + b2v[r];
            v = fmaxf(v, 0.01f * v);
            y2[((size_t)h * WW + w) * D2 + e0 + lg * 4 + r] = f2bf(v);
        }
    }
}

// ------- Stage 3+4 fused: per-h block; full E in-block; writes final out ------
__global__ __launch_bounds__(512) void gemm3_kernel(
    const unsigned short* __restrict__ y2, const float* __restrict__ w3,
    const float* __restrict__ b3, const float* __restrict__ w4,
    const float* __restrict__ b4, float* __restrict__ out)
{
    __shared__ __align__(16) unsigned char lds[WW * 256 + 2 * WW * 4];  // 160512 B
    float* pk = reinterpret_cast<float*>(&lds[WW * 256]);               // pk[2][608]
    const int h = blockIdx.x;
    const int tid = threadIdx.x;
    const int lane = tid & 63, wv = tid >> 6;
    const int l15 = lane & 15, lg = lane >> 4;
    const int e0 = wv * 128;                        // 8 waves x 128 = 1024

    for (int i = tid; i < 2 * WW; i += 512) pk[i] = 0.f;

    // stage y2[h]
    {
        const unsigned char* src = reinterpret_cast<const unsigned char*>(y2 + (size_t)h * WW * D2);
        #pragma unroll
        for (int i = 0; i < 19; ++i) {
            const int byte = (i * 512 + tid) * 16;
            const int row  = byte >> 8;
            const int slot = (byte >> 4) & 15;
            uint4 val = *reinterpret_cast<const uint4*>(src + byte);
            const int dst = row * 256 + ((slot ^ (row & 7)) << 4);
            *reinterpret_cast<uint4*>(&lds[dst]) = val;
        }
    }
    __syncthreads();

    for (int mt = 0; mt < 2; ++mt) {
        const int e64 = e0 + mt * 64;
        // A frags: 64 e-rows x K=128, f32 -> bf16 in regs
        bf16x8 a[4][4];
        #pragma unroll
        for (int mf = 0; mf < 4; ++mf)
            #pragma unroll
            for (int kc = 0; kc < 4; ++kc)
                a[mf][kc] = cvt8c(w3 + ((size_t)h * D3 + e64 + mf * 16 + l15) * D2 + kc * 32 + lg * 8);
        f32x4 b3v[4], w40[4], w41[4];
        #pragma unroll
        for (int mf = 0; mf < 4; ++mf) {
            b3v[mf] = *reinterpret_cast<const f32x4*>(b3 + (size_t)h * D3 + e64 + mf * 16 + lg * 4);
            w40[mf] = *reinterpret_cast<const f32x4*>(w4 + (size_t)h * 2 * D3 + e64 + mf * 16 + lg * 4);
            w41[mf] = *reinterpret_cast<const f32x4*>(w4 + (size_t)h * 2 * D3 + D3 + e64 + mf * 16 + lg * 4);
        }

        for (int nf = 0; nf < 38; ++nf) {
            const int w = nf * 16 + l15;
            bf16x8 b[4];
            #pragma unroll
            for (int kc = 0; kc < 4; ++kc) {
                const int sl = (kc * 4 + lg) ^ (w & 7);
                b[kc] = *reinterpret_cast<const bf16x8*>(&lds[(size_t)w * 256 + sl * 16]);
            }
            float p0 = 0.f, p1 = 0.f;
            #pragma unroll
            for (int mf = 0; mf < 4; ++mf) {
                f32x4 t = {};
                #pragma unroll
                for (int kc = 0; kc < 4; ++kc)
                    t = __builtin_amdgcn_mfma_f32_16x16x32_bf16(a[mf][kc], b[kc], t, 0, 0, 0);
                #pragma unroll
                for (int r = 0; r < 4; ++r) {
                    float v = t[r] + b3v[mf][r];
                    v = fmaxf(v, 0.01f * v);          // lrelu
                    p0 = fmaf(w40[mf][r], v, p0);
                    p1 = fmaf(w41[mf][r], v, p1);
                }
            }
            // reduce over lane groups (rows) -> per-column sums
            p0 += __shfl_xor(p0, 16); p0 += __shfl_xor(p0, 32);
            p1 += __shfl_xor(p1, 16); p1 += __shfl_xor(p1, 32);
            if (lane < 16) {
                atomicAdd(&pk[w], p0);
                atomicAdd(&pk[WW + w], p1);
            }
        }
    }
    __syncthreads();

    const float bb0 = b4[h * 2 + 0], bb1 = b4[h * 2 + 1];
    for (int i = tid; i < WW; i += 512) {
        float s0 = pk[i] + bb0;
        float s1 = pk[WW + i] + bb1;
        out[(size_t)h * WW + i] = s0;
        out[(size_t)HWPROD + (size_t)h * WW + i] = fmaxf(s1, 0.01f * s1);
    }
}

extern "C" void kernel_launch(void* const* d_in, const int* in_sizes, int n_in,
                              void* d_out, int out_size, void* d_ws, size_t ws_size,
                              hipStream_t stream) {
    const float* x  = (const float*)d_in[0];
    const float* w1 = (const float*)d_in[1];
    const float* b1 = (const float*)d_in[2];
    const float* w2 = (const float*)d_in[3];
    const float* b2 = (const float*)d_in[4];
    const float* w3 = (const float*)d_in[5];
    const float* b3 = (const float*)d_in[6];
    const float* w4 = (const float*)d_in[7];
    const float* b4 = (const float*)d_in[8];
    float* out = (float*)d_out;

    char* ws = (char*)d_ws;
    size_t off = 0;
    unsigned short* y1 = (unsigned short*)(ws + off); off += (size_t)HWPROD * D1 * 2;  // 69.73 MB
    // region B: xt (34.87 MB) then reused as y2 (69.73 MB) — disjoint lifetimes
    char* regionB = ws + off; off += (size_t)HWPROD * D2 * 2;
    unsigned short* xt = (unsigned short*)regionB;
    unsigned short* y2 = (unsigned short*)regionB;
    unsigned short* w1t = (unsigned short*)(ws + off); off += (size_t)9 * D1 * 64 * 2; // 147 KB

    transpose_x_kernel<<<HWPROD / 256, 256, 0, stream>>>(x, xt);
    convert_w1_kernel<<<(9 * D1 * 64 + 255) / 256, 256, 0, stream>>>(w1, w1t);

    conv_kernel <<<dim3(2, HH), 512, 0, stream>>>(xt, w1t, b1, y1);
    gemm2_kernel<<<HH, 512, 0, stream>>>(y1, w2, b2, y2);
    gemm3_kernel<<<HH, 512, 0, stream>>>(y2, w3, b3, w4, b4, out);
}